// Round 8
// baseline (153529.333 us; speedup 1.0000x reference)
//
#include <hip/hip_runtime.h>
#include <hip/hip_fp16.h>
#include <cstdint>
#include <cstddef>

// KNN regressor v8 — one-chunk-per-XCD L2 affinity + cheap raw-dot detection.
//   score[n] = tsq[n] - 2*dot(q, x_n)
// approx dot via fp16 split (qh+qr)·xh; |approx-exact| <= E_q = 2|q|·maxXr+0.02.
// Pipeline: memset -> prep_all -> sample_T -> knn_main -> finalize(+fallback).
// knn_main: QT=16 queries/block, NCH=8 chunks (ch = lb&7 == XCD -> one 3.2 MB
//   chunk resident per XCD L2, v6-measured 99% hit). Detection on raw dot:
//   hit iff max_rg(dot) > (tsq - maxTh)/2 - slack  (strictly conservative),
//   exact per-element check only on group hit. LDS candidate lists, no global
//   atomics; dump to fixed slots. finalize merges 8 sorted lists, exact fp32
//   rescore of top-64, verification, inline brute-force fallback on failure.
//
// MFMA 16x16x32 f16 layouts (HW-verified, learn_hip m89/m91/m120):
//   A[m][k]: m=lane&15, k=(lane>>4)*8+j ; B[k][n]: n=lane&15, k=(lane>>4)*8+j
//   C[m][n]: n=lane&15, m=(lane>>4)*4+reg
// Xs swizzle: seg s=(n>>4)*4+ks holds at half8-idx s*64+L the halves of
//   row (n&~15)+(L&15), k = ks*32+(L>>4)*8..+8  (1 KB per segment).

constexpr int Q_  = 4096;
constexpr int N_  = 100000;
constexpr int D_  = 128;
constexpr int K_  = 32;

constexpr int QT    = 16;             // queries per block (one 16-row A tile)
constexpr int BN    = 256;            // n per iteration
constexpr int NCH   = 8;              // chunks == XCDs (ch = lb & 7)
constexpr int CHUNK = 12544;          // 49*256
constexpr int ITERS = CHUNK / BN;     // 49
constexpr int NPAD  = NCH * CHUNK;    // 100352
constexpr int CW    = 64;             // per-(query,chunk) candidate capacity
constexpr int QTS   = 16;             // sample_T queries per block
constexpr int SAMP_M      = 8192;
constexpr int SAMP_STRIDE = 12;
constexpr int SAMP_OFF    = 5;        // max n = 8191*12+5 = 98297 < N_
constexpr int SAMP_ITERS  = SAMP_M / BN;   // 32

// prep_all grid sections
constexpr int XS_B  = NPAD / 64;      // 1568 blocks: Xs + tsq + maxXr2
constexpr int SAM_B = SAMP_M / 64;    // 128 blocks: Xsam + tsqS
constexpr int PQ_B  = Q_ / 4;         // 1024 blocks: Qh/Qr/qsq

typedef __attribute__((ext_vector_type(8))) _Float16 half8;
typedef __attribute__((ext_vector_type(4))) float    floatx4;
typedef unsigned long long ull;

#define DEV __device__ __forceinline__
constexpr ull DEADC = ~0ull;

DEV ull pack_cand(float score, unsigned int n) {
    unsigned int s = __float_as_uint(score);
    s = (s & 0x80000000u) ? ~s : (s | 0x80000000u);   // monotone u32 key
    return ((ull)s << 32) | (ull)n;
}
DEV float unpack_score(ull k) {
    unsigned int s = (unsigned int)(k >> 32);
    s = (s & 0x80000000u) ? (s ^ 0x80000000u) : ~s;
    return __uint_as_float(s);
}
DEV ull u64min(ull a, ull b) { return a < b ? a : b; }
DEV float inf_f() { return __int_as_float(0x7f800000); }

DEV ull bitonic64(ull v, int L) {            // full sort, ascending
    #pragma unroll
    for (int k2 = 2; k2 <= 64; k2 <<= 1)
        #pragma unroll
        for (int j2 = k2 >> 1; j2 >= 1; j2 >>= 1) {
            ull o = __shfl_xor(v, j2);
            bool up = ((L & k2) == 0);
            bool lo = ((L & j2) == 0);
            ull mn = u64min(v, o), mx = v ^ o ^ mn;
            v = (lo == up) ? mn : mx;
        }
    return v;
}
DEV ull bimerge64(ull v, int L) {            // sort a bitonic seq, ascending
    #pragma unroll
    for (int j2 = 32; j2 >= 1; j2 >>= 1) {
        ull o = __shfl_xor(v, j2);
        ull mn = u64min(v, o), mx = v ^ o ^ mn;
        v = ((L & j2) == 0) ? mn : mx;
    }
    return v;
}

// ------------------------------------------------------------- prep_all -----
// Ranged sections: [0,XS_B) Xs/tsq/maxXr2; [XS_B,+SAM_B) Xsam/tsqS;
// [XS_B+SAM_B,+PQ_B) Qh/Qr/qsq. All sections branch wave-uniformly.
__global__ void prep_all(const float* __restrict__ X, const float* __restrict__ Qm,
                         __half* __restrict__ Xs, float* __restrict__ tsq,
                         unsigned* __restrict__ maxXr2,
                         __half* __restrict__ Xsam, float* __restrict__ tsqS,
                         __half* __restrict__ Qh, __half* __restrict__ Qr,
                         float* __restrict__ qsq)
{
    const int tid = threadIdx.x, L = tid & 63, wv = tid >> 6;
    const int bx = blockIdx.x;
    const int am = L & 15, aq = L >> 4;

    if (bx < XS_B) {
        int t16 = bx * 4 + wv;
        int r = t16 * 16 + am;
        float ssq = 0.f, xr2 = 0.f;
        #pragma unroll
        for (int ks = 0; ks < 4; ++ks) {
            int c = ks * 32 + aq * 8;
            float v0=0,v1=0,v2=0,v3=0,v4=0,v5=0,v6=0,v7=0;
            if (r < N_) {
                float4 a = *(const float4*)(X + (size_t)r * D_ + c);
                float4 b = *(const float4*)(X + (size_t)r * D_ + c + 4);
                v0=a.x; v1=a.y; v2=a.z; v3=a.w; v4=b.x; v5=b.y; v6=b.z; v7=b.w;
            }
            half8 h;
            h[0]=(_Float16)v0; h[1]=(_Float16)v1; h[2]=(_Float16)v2; h[3]=(_Float16)v3;
            h[4]=(_Float16)v4; h[5]=(_Float16)v5; h[6]=(_Float16)v6; h[7]=(_Float16)v7;
            float r0=v0-(float)h[0], r1=v1-(float)h[1], r2=v2-(float)h[2], r3=v3-(float)h[3];
            float r4=v4-(float)h[4], r5=v5-(float)h[5], r6=v6-(float)h[6], r7=v7-(float)h[7];
            ssq += v0*v0+v1*v1+v2*v2+v3*v3+v4*v4+v5*v5+v6*v6+v7*v7;
            xr2 += r0*r0+r1*r1+r2*r2+r3*r3+r4*r4+r5*r5+r6*r6+r7*r7;
            *(half8*)(Xs + ((size_t)(t16 * 4 + ks)) * 512 + L * 8) = h;
        }
        ssq += __shfl_xor(ssq, 16); ssq += __shfl_xor(ssq, 32);
        xr2 += __shfl_xor(xr2, 16); xr2 += __shfl_xor(xr2, 32);
        if (aq == 0) tsq[r] = (r < N_) ? ssq : inf_f();
        float m = xr2;
        m = fmaxf(m, __shfl_xor(m, 1)); m = fmaxf(m, __shfl_xor(m, 2));
        m = fmaxf(m, __shfl_xor(m, 4)); m = fmaxf(m, __shfl_xor(m, 8));
        if (L == 0) atomicMax(maxXr2, __float_as_uint(m));
    } else if (bx < XS_B + SAM_B) {
        int t16 = (bx - XS_B) * 4 + wv;
        int j = t16 * 16 + am;
        int n = j * SAMP_STRIDE + SAMP_OFF;       // < N_
        float ssq = 0.f;
        #pragma unroll
        for (int ks = 0; ks < 4; ++ks) {
            int c = ks * 32 + aq * 8;
            float4 a = *(const float4*)(X + (size_t)n * D_ + c);
            float4 b = *(const float4*)(X + (size_t)n * D_ + c + 4);
            half8 h;
            h[0]=(_Float16)a.x; h[1]=(_Float16)a.y; h[2]=(_Float16)a.z; h[3]=(_Float16)a.w;
            h[4]=(_Float16)b.x; h[5]=(_Float16)b.y; h[6]=(_Float16)b.z; h[7]=(_Float16)b.w;
            ssq += a.x*a.x + a.y*a.y + a.z*a.z + a.w*a.w
                 + b.x*b.x + b.y*b.y + b.z*b.z + b.w*b.w;
            *(half8*)(Xsam + ((size_t)(t16 * 4 + ks)) * 512 + L * 8) = h;
        }
        ssq += __shfl_xor(ssq, 16); ssq += __shfl_xor(ssq, 32);
        if (aq == 0) tsqS[j] = ssq;
    } else {
        int r = (bx - XS_B - SAM_B) * 4 + wv;     // < Q_
        float2 x = *(const float2*)(Qm + (size_t)r * D_ + 2 * L);
        __half h0 = __float2half(x.x), h1 = __float2half(x.y);
        size_t o = (size_t)r * D_ + 2 * L;
        Qh[o] = h0; Qh[o + 1] = h1;
        Qr[o]     = __float2half(x.x - __half2float(h0));
        Qr[o + 1] = __float2half(x.y - __half2float(h1));
        float s = x.x * x.x + x.y * x.y;
        s += __shfl_xor(s, 32); s += __shfl_xor(s, 16); s += __shfl_xor(s, 8);
        s += __shfl_xor(s, 4);  s += __shfl_xor(s, 2);  s += __shfl_xor(s, 1);
        if (L == 0) qsq[r] = s;
    }
}

// ---------------------------------------------------------- sample_T --------
// T_q = 16th smallest of per-lane-top2 approx scores over the 8192 sample.
__global__ __launch_bounds__(256, 2) void sample_T(
    const __half* __restrict__ Qh, const __half* __restrict__ Qr,
    const __half* __restrict__ Xsam, const float* __restrict__ tsqS,
    const float* __restrict__ qsq, const unsigned* __restrict__ maxXr2,
    float* __restrict__ Teff, float* __restrict__ rawT, float* __restrict__ EwA)
{
    __shared__ float sT[QTS][130];
    const int tid = threadIdx.x, L = tid & 63, wv = tid >> 6;
    const int qbase = blockIdx.x * QTS;
    const int nwv = wv * 64;
    const int am = L & 15, aq = L >> 4;

    half8 afh[4], afr[4];
    #pragma unroll
    for (int ks = 0; ks < 4; ++ks) {
        size_t o = (size_t)(qbase + am) * D_ + ks * 32 + aq * 8;
        afh[ks] = *(const half8*)(Qh + o);
        afr[ks] = *(const half8*)(Qr + o);
    }
    const half8* sp = (const half8*)Xsam;

    float t2a[4], t2b[4];
    #pragma unroll
    for (int rg = 0; rg < 4; ++rg) { t2a[rg] = inf_f(); t2b[rg] = inf_f(); }

    #pragma unroll 1
    for (int it = 0; it < SAMP_ITERS; ++it) {
        const int nbase = it * BN;
        const size_t segb = (size_t)((nbase + nwv) >> 4) * 4;
        floatx4 acc[4] = {};
        #pragma unroll
        for (int ks = 0; ks < 4; ++ks) {
            half8 bf[4];
            #pragma unroll
            for (int nt = 0; nt < 4; ++nt)
                bf[nt] = sp[(segb + nt * 4 + ks) * 64 + L];
            #pragma unroll
            for (int nt = 0; nt < 4; ++nt) {
                acc[nt] = __builtin_amdgcn_mfma_f32_16x16x32_f16(
                    afh[ks], bf[nt], acc[nt], 0, 0, 0);
                acc[nt] = __builtin_amdgcn_mfma_f32_16x16x32_f16(
                    afr[ks], bf[nt], acc[nt], 0, 0, 0);
            }
        }
        float ts[4];
        #pragma unroll
        for (int nt = 0; nt < 4; ++nt)
            ts[nt] = tsqS[nbase + nwv + nt * 16 + am];
        #pragma unroll
        for (int rg = 0; rg < 4; ++rg) {
            float m1 = t2a[rg], m2 = t2b[rg];
            #pragma unroll
            for (int nt = 0; nt < 4; ++nt) {
                float v = ts[nt] - 2.f * acc[nt][rg];
                if (v < m2) { if (v < m1) { m2 = m1; m1 = v; } else m2 = v; }
            }
            t2a[rg] = m1; t2b[rg] = m2;
        }
    }
    #pragma unroll
    for (int rg = 0; rg < 4; ++rg) {
        int q = aq * 4 + rg;
        sT[q][wv * 32 + am * 2 + 0] = t2a[rg];
        sT[q][wv * 32 + am * 2 + 1] = t2b[rg];
    }
    __syncthreads();

    #pragma unroll 1
    for (int j = 0; j < 4; ++j) {
        int q = wv * 4 + j;
        float a = sT[q][2 * L], b = sT[q][2 * L + 1];
        float g = 0.f;
        #pragma unroll 1
        for (int r = 0; r < 16; ++r) {
            float mn = fminf(a, b);
            mn = fminf(mn, __shfl_xor(mn, 32)); mn = fminf(mn, __shfl_xor(mn, 16));
            mn = fminf(mn, __shfl_xor(mn, 8));  mn = fminf(mn, __shfl_xor(mn, 4));
            mn = fminf(mn, __shfl_xor(mn, 2));  mn = fminf(mn, __shfl_xor(mn, 1));
            g = mn;
            ull ba = __ballot(a == g);
            if (ba) { if (L == __ffsll(ba) - 1) a = inf_f(); }
            else    { ull bb = __ballot(b == g); if (L == __ffsll(bb) - 1) b = inf_f(); }
        }
        if (L == 0) {
            int gq = qbase + q;
            float e = 2.f * sqrtf(qsq[gq]) * sqrtf(__uint_as_float(*maxXr2)) + 0.02f;
            rawT[gq] = g; EwA[gq] = e; Teff[gq] = g + e;
        }
    }
}

// ------------------------------------------------------------- main ---------
__global__ __launch_bounds__(256, 4) void knn_main(
    const __half* __restrict__ Qh, const __half* __restrict__ Qr,
    const __half* __restrict__ Xs, const float* __restrict__ tsq,
    const float* __restrict__ Teff, ull* __restrict__ candG,
    int* __restrict__ cntC, int* __restrict__ flagF)
{
    __shared__ ull candL[QT][CW];                 // 8 KB
    __shared__ int cntL[QT];

    const int tid = threadIdx.x, L = tid & 63, wv = tid >> 6;
    const int lb = blockIdx.x, ch = lb & 7;       // == XCD: one chunk per L2
    const int qbase = (lb >> 3) * QT, chBase = ch * CHUNK, nwv = wv * 64;
    const int am = L & 15, aq = L >> 4;

    if (tid < QT) cntL[tid] = 0;
    __syncthreads();                              // barrier #1

    // per-lane thresholds for queries aq*4+rg; conservative group bound
    float th[4];
    #pragma unroll
    for (int rg = 0; rg < 4; ++rg)
        th[rg] = Teff[qbase + aq * 4 + rg];
    float maxTh = fmaxf(fmaxf(th[0], th[1]), fmaxf(th[2], th[3]));
    const float negHalfMaxTh = -0.5f * maxTh - 1e-3f;   // slack: strictly conservative

    half8 afh[4], afr[4];
    #pragma unroll
    for (int ks = 0; ks < 4; ++ks) {
        size_t o = (size_t)(qbase + am) * D_ + ks * 32 + aq * 8;
        afh[ks] = *(const half8*)(Qh + o);
        afr[ks] = *(const half8*)(Qr + o);
    }
    const half8* sp = (const half8*)Xs;

    // preload iter0 ks0 B-fragments
    half8 bc[4], bn[4];
    {
        size_t s0 = (size_t)((chBase + nwv) >> 4) * 4;
        #pragma unroll
        for (int nt = 0; nt < 4; ++nt)
            bc[nt] = sp[(s0 + nt * 4) * 64 + L];
    }

    #pragma unroll 1
    for (int it = 0; it < ITERS; ++it) {
        const int nbase = chBase + it * BN;
        const size_t sg  = (size_t)((nbase + nwv) >> 4) * 4;
        const size_t sgN = sg + 64;               // next iter (BN/16*4)
        float ts[4];
        #pragma unroll
        for (int nt = 0; nt < 4; ++nt)
            ts[nt] = tsq[nbase + nwv + nt * 16 + am];

        floatx4 acc[4] = {};
        #pragma unroll
        for (int ks = 0; ks < 4; ++ks) {
            const bool hasNext = (ks < 3) || (it + 1 < ITERS);
            if (hasNext) {
                const size_t sb = (ks < 3) ? (sg + ks + 1) : sgN;
                #pragma unroll
                for (int nt = 0; nt < 4; ++nt)
                    bn[nt] = sp[(sb + nt * 4) * 64 + L];
            }
            #pragma unroll
            for (int nt = 0; nt < 4; ++nt) {
                acc[nt] = __builtin_amdgcn_mfma_f32_16x16x32_f16(
                    afh[ks], bc[nt], acc[nt], 0, 0, 0);
                acc[nt] = __builtin_amdgcn_mfma_f32_16x16x32_f16(
                    afr[ks], bc[nt], acc[nt], 0, 0, 0);
            }
            if (hasNext) {
                #pragma unroll
                for (int nt = 0; nt < 4; ++nt) bc[nt] = bn[nt];
            }
        }

        // cheap conservative detection on raw dot:
        //   score < th  <=>  dot > (ts - th)/2 ; group bound uses maxTh+slack.
        unsigned hit = 0;
        #pragma unroll
        for (int nt = 0; nt < 4; ++nt) {
            float mx = fmaxf(fmaxf(acc[nt][0], acc[nt][1]),
                             fmaxf(acc[nt][2], acc[nt][3]));
            float Gm = fmaf(0.5f, ts[nt], negHalfMaxTh);
            if (mx > Gm) hit |= 1u << nt;
        }
        if (__any(hit != 0)) {
            #pragma unroll
            for (int nt = 0; nt < 4; ++nt) {
                if (!__any(hit & (1u << nt))) continue;
                unsigned n = (unsigned)(nbase + nwv + nt * 16 + am);
                #pragma unroll
                for (int rg = 0; rg < 4; ++rg) {
                    float s = fmaf(-2.f, acc[nt][rg], ts[nt]);
                    if (s < th[rg]) {
                        int q = aq * 4 + rg;
                        int pos = atomicAdd(&cntL[q], 1);     // LDS atomic
                        if (pos < CW)
                            candL[q][pos] = pack_cand(s, n);
                        else
                            flagF[qbase + q] = 1;             // ~never
                    }
                }
            }
        }
    }

    __syncthreads();                              // barrier #2 (pre-dump)

    // dump per-(query,chunk) lists to fixed global slots (no atomics)
    #pragma unroll 1
    for (int j = 0; j < 4; ++j) {
        int q = wv * 4 + j;
        int gq = qbase + q;
        int c = cntL[q];
        int cc = c < CW ? c : CW;
        if (L < cc)
            candG[((size_t)gq * NCH + ch) * CW + L] = candL[q][L];
        if (L == 0)
            cntC[gq * NCH + ch] = cc;
    }
}

// ---------------------------------------- finalize (+ inline fallback) ------
__global__ void finalize(const ull* __restrict__ candG, const int* __restrict__ cntC,
                         const int* __restrict__ flagF, const float* __restrict__ Qm,
                         const float* __restrict__ X, const float* __restrict__ tsq,
                         const float* __restrict__ rawT, const float* __restrict__ EwA,
                         const float* __restrict__ Ytr, float* __restrict__ out)
{
    int L = threadIdx.x & 63;
    int q = blockIdx.x * 4 + (threadIdx.x >> 6);  // one wave per query
    bool bad = (flagF[q] != 0);
    float result = 0.f;

    if (!bad) {
        int cg = (L < NCH) ? cntC[q * NCH + L] : 0;
        int ctot = cg;
        ctot += __shfl_xor(ctot, 32); ctot += __shfl_xor(ctot, 16);
        ctot += __shfl_xor(ctot, 8);  ctot += __shfl_xor(ctot, 4);
        ctot += __shfl_xor(ctot, 2);  ctot += __shfl_xor(ctot, 1);
        if (ctot < K_) bad = true;
        else {
            // merge 8 lists -> global top-64 by approx (ascending)
            ull s = DEADC;
            #pragma unroll 1
            for (int g = 0; g < NCH; ++g) {
                int c_g = __shfl(cg, g);
                if (c_g == 0) continue;
                ull v = (L < c_g) ? candG[((size_t)q * NCH + g) * CW + L] : DEADC;
                v = bitonic64(v, L);
                ull w = __shfl(v, 63 - L);
                s = bimerge64(u64min(s, w), L);
            }
            int cr = ctot < 64 ? ctot : 64;
            unsigned n = (unsigned)(s & 0xffffffffu);
            ull pe = DEADC;
            if (L < cr) {
                const float4* xp = (const float4*)(X + (size_t)n * D_);
                const float4* qp = (const float4*)(Qm + (size_t)q * D_);
                float d = 0.f;
                #pragma unroll 8
                for (int i = 0; i < 32; ++i) {
                    float4 xv = xp[i], qv = qp[i];
                    d += qv.x * xv.x + qv.y * xv.y + qv.z * xv.z + qv.w * xv.w;
                }
                pe = pack_cand(tsq[n] - 2.f * d, n);
            }
            ull pe2 = bitonic64(pe, L);
            float exact31 = unpack_score(__shfl(pe2, K_ - 1));
            bool ok = exact31 < rawT[q];
            if (ctot > 64) {
                float A63 = unpack_score(__shfl(s, 63));
                ok = ok && (A63 - EwA[q] > exact31);
            }
            if (!ok) bad = true;
            else {
                float ys = 0.f;
                if (L < K_) ys = Ytr[(unsigned)(pe2 & 0xffffffffu)];
                ys += __shfl_xor(ys, 32); ys += __shfl_xor(ys, 16);
                ys += __shfl_xor(ys, 8);  ys += __shfl_xor(ys, 4);
                ys += __shfl_xor(ys, 2);  ys += __shfl_xor(ys, 1);
                result = ys * (1.f / K_);
            }
        }
    }

    if (bad) {   // brute-force exact top-32 (wave-uniform, ~never taken)
        const float4* qp = (const float4*)(Qm + (size_t)q * D_);
        ull last = 0;
        float ysum = 0.f;
        for (int r = 0; r < K_; ++r) {
            ull best = DEADC;
            for (int j = 0; j < NPAD / 64; ++j) {
                int n = j * 64 + L;
                if (n < N_) {
                    const float4* xp = (const float4*)(X + (size_t)n * D_);
                    float d = 0.f;
                    #pragma unroll 4
                    for (int i = 0; i < 32; ++i) {
                        float4 xv = xp[i], qv = qp[i];
                        d += qv.x * xv.x + qv.y * xv.y + qv.z * xv.z + qv.w * xv.w;
                    }
                    ull k = pack_cand(tsq[n] - 2.f * d, n);
                    if (k > last && k < best) best = k;
                }
            }
            best = u64min(best, __shfl_xor(best, 32));
            best = u64min(best, __shfl_xor(best, 16));
            best = u64min(best, __shfl_xor(best, 8));
            best = u64min(best, __shfl_xor(best, 4));
            best = u64min(best, __shfl_xor(best, 2));
            best = u64min(best, __shfl_xor(best, 1));
            if (L == 0) ysum += Ytr[(unsigned)(best & 0xffffffffu)];
            last = best;
        }
        result = ysum * (1.f / K_);
    }
    if (L == 0) out[q] = result;
}

// ------------------------------------------------------------- launch -------
extern "C" void kernel_launch(void* const* d_in, const int* in_sizes, int n_in,
                              void* d_out, int out_size, void* d_ws, size_t ws_size,
                              hipStream_t stream)
{
    const float* Qm  = (const float*)d_in[0];   // [4096,128]
    const float* X   = (const float*)d_in[1];   // [100000,128]
    const float* Ytr = (const float*)d_in[2];   // [100000]
    float* out = (float*)d_out;                 // [4096]

    char* w = (char*)d_ws;
    auto alloc = [&](size_t bytes) {
        char* p = w; w += (bytes + 255) & ~(size_t)255; return p;
    };
    __half* Xs   = (__half*)  alloc((size_t)NPAD * D_ * 2);     // 25.7 MB
    __half* Qh   = (__half*)  alloc((size_t)Q_ * D_ * 2);       // 1 MB
    __half* Qr   = (__half*)  alloc((size_t)Q_ * D_ * 2);       // 1 MB
    float*  ts   = (float*)   alloc((size_t)NPAD * 4);          // 0.4 MB
    __half* Xsm  = (__half*)  alloc((size_t)SAMP_M * D_ * 2);   // 2 MB
    float*  tsS  = (float*)   alloc((size_t)SAMP_M * 4);        // 32 KB
    ull*    cd   = (ull*)     alloc((size_t)Q_ * NCH * CW * 8); // 16.8 MB
    int*    cnC  = (int*)     alloc((size_t)Q_ * NCH * 4);      // 128 KB
    int*    flg  = (int*)     alloc((size_t)Q_ * 4);            // 16 KB
    unsigned* mxr= (unsigned*)alloc(256);
    float*  Tef  = (float*)   alloc((size_t)Q_ * 4);
    float*  rwT  = (float*)   alloc((size_t)Q_ * 4);
    float*  Ew   = (float*)   alloc((size_t)Q_ * 4);
    float*  qs   = (float*)   alloc((size_t)Q_ * 4);            // total ~47 MB

    // zero flags + maxXr2 (flg is 16 KB = 256-multiple, mxr adjacent)
    hipMemsetAsync(flg, 0, (size_t)Q_ * 4 + 256, stream);

    prep_all<<<XS_B + SAM_B + PQ_B, 256, 0, stream>>>(
        X, Qm, Xs, ts, mxr, Xsm, tsS, Qh, Qr, qs);
    sample_T<<<Q_ / QTS, 256, 0, stream>>>(Qh, Qr, Xsm, tsS, qs, mxr, Tef, rwT, Ew);
    knn_main<<<(Q_ / QT) * NCH, 256, 0, stream>>>(Qh, Qr, Xs, ts, Tef, cd, cnC, flg);
    finalize<<<Q_ / 4, 256, 0, stream>>>(cd, cnC, flg, Qm, X, ts, rwT, Ew, Ytr, out);
}

// Round 9
// 534.145 us; speedup vs baseline: 287.4301x; 287.4301x over previous
//
#include <hip/hip_runtime.h>
#include <hip/hip_fp16.h>
#include <cstdint>
#include <cstddef>

// KNN regressor v9 — v8 + overflow-proof capacity + cheap fallback.
//   score[n] = tsq[n] - 2*dot(q, x_n)
// approx dot via fp16 split (qh+qr)·xh; |approx-exact| <= E_q = 2|q|·maxXr+0.02.
// v8 failure mode (measured r8): rawT = 16th-of-8192-sample order stat has
// population rank ~Gamma(16)/0.082 (mean 195, sigma 49, heavy right tail);
// for ~1/4096 queries a chunk exceeded CW=64 -> flag -> 183 ms single-wave
// brute force. Fix: CW=128 (overflow P~1e-13) + single-pass thresholded
// fallback (typ. 1 scan, not 32).
//
// MFMA 16x16x32 f16 layouts (HW-verified, learn_hip m89/m91/m120):
//   A[m][k]: m=lane&15, k=(lane>>4)*8+j ; B[k][n]: n=lane&15, k=(lane>>4)*8+j
//   C[m][n]: n=lane&15, m=(lane>>4)*4+reg
// Xs swizzle: seg s=(n>>4)*4+ks holds at half8-idx s*64+L the halves of
//   row (n&~15)+(L&15), k = ks*32+(L>>4)*8..+8  (1 KB per segment).

constexpr int Q_  = 4096;
constexpr int N_  = 100000;
constexpr int D_  = 128;
constexpr int K_  = 32;

constexpr int QT    = 16;             // queries per block (one 16-row A tile)
constexpr int BN    = 256;            // n per iteration
constexpr int NCH   = 8;              // chunks == XCDs (ch = lb & 7)
constexpr int CHUNK = 12544;          // 49*256
constexpr int ITERS = CHUNK / BN;     // 49
constexpr int NPAD  = NCH * CHUNK;    // 100352
constexpr int CW    = 128;            // per-(query,chunk) capacity (P_ovf~1e-13)
constexpr int QTS   = 16;             // sample_T queries per block
constexpr int SAMP_M      = 8192;
constexpr int SAMP_STRIDE = 12;
constexpr int SAMP_OFF    = 5;        // max n = 8191*12+5 = 98297 < N_
constexpr int SAMP_ITERS  = SAMP_M / BN;   // 32

// prep_all grid sections
constexpr int XS_B  = NPAD / 64;      // 1568 blocks: Xs + tsq + maxXr2
constexpr int SAM_B = SAMP_M / 64;    // 128 blocks: Xsam + tsqS
constexpr int PQ_B  = Q_ / 4;         // 1024 blocks: Qh/Qr/qsq

typedef __attribute__((ext_vector_type(8))) _Float16 half8;
typedef __attribute__((ext_vector_type(4))) float    floatx4;
typedef unsigned long long ull;

#define DEV __device__ __forceinline__
constexpr ull DEADC = ~0ull;

DEV ull pack_cand(float score, unsigned int n) {
    unsigned int s = __float_as_uint(score);
    s = (s & 0x80000000u) ? ~s : (s | 0x80000000u);   // monotone u32 key
    return ((ull)s << 32) | (ull)n;
}
DEV float unpack_score(ull k) {
    unsigned int s = (unsigned int)(k >> 32);
    s = (s & 0x80000000u) ? (s ^ 0x80000000u) : ~s;
    return __uint_as_float(s);
}
DEV ull u64min(ull a, ull b) { return a < b ? a : b; }
DEV float inf_f() { return __int_as_float(0x7f800000); }

DEV ull bitonic64(ull v, int L) {            // full sort, ascending
    #pragma unroll
    for (int k2 = 2; k2 <= 64; k2 <<= 1)
        #pragma unroll
        for (int j2 = k2 >> 1; j2 >= 1; j2 >>= 1) {
            ull o = __shfl_xor(v, j2);
            bool up = ((L & k2) == 0);
            bool lo = ((L & j2) == 0);
            ull mn = u64min(v, o), mx = v ^ o ^ mn;
            v = (lo == up) ? mn : mx;
        }
    return v;
}
DEV ull bimerge64(ull v, int L) {            // sort a bitonic seq, ascending
    #pragma unroll
    for (int j2 = 32; j2 >= 1; j2 >>= 1) {
        ull o = __shfl_xor(v, j2);
        ull mn = u64min(v, o), mx = v ^ o ^ mn;
        v = ((L & j2) == 0) ? mn : mx;
    }
    return v;
}

// ------------------------------------------------------------- prep_all -----
__global__ void prep_all(const float* __restrict__ X, const float* __restrict__ Qm,
                         __half* __restrict__ Xs, float* __restrict__ tsq,
                         unsigned* __restrict__ maxXr2,
                         __half* __restrict__ Xsam, float* __restrict__ tsqS,
                         __half* __restrict__ Qh, __half* __restrict__ Qr,
                         float* __restrict__ qsq)
{
    const int tid = threadIdx.x, L = tid & 63, wv = tid >> 6;
    const int bx = blockIdx.x;
    const int am = L & 15, aq = L >> 4;

    if (bx < XS_B) {
        int t16 = bx * 4 + wv;
        int r = t16 * 16 + am;
        float ssq = 0.f, xr2 = 0.f;
        #pragma unroll
        for (int ks = 0; ks < 4; ++ks) {
            int c = ks * 32 + aq * 8;
            float v0=0,v1=0,v2=0,v3=0,v4=0,v5=0,v6=0,v7=0;
            if (r < N_) {
                float4 a = *(const float4*)(X + (size_t)r * D_ + c);
                float4 b = *(const float4*)(X + (size_t)r * D_ + c + 4);
                v0=a.x; v1=a.y; v2=a.z; v3=a.w; v4=b.x; v5=b.y; v6=b.z; v7=b.w;
            }
            half8 h;
            h[0]=(_Float16)v0; h[1]=(_Float16)v1; h[2]=(_Float16)v2; h[3]=(_Float16)v3;
            h[4]=(_Float16)v4; h[5]=(_Float16)v5; h[6]=(_Float16)v6; h[7]=(_Float16)v7;
            float r0=v0-(float)h[0], r1=v1-(float)h[1], r2=v2-(float)h[2], r3=v3-(float)h[3];
            float r4=v4-(float)h[4], r5=v5-(float)h[5], r6=v6-(float)h[6], r7=v7-(float)h[7];
            ssq += v0*v0+v1*v1+v2*v2+v3*v3+v4*v4+v5*v5+v6*v6+v7*v7;
            xr2 += r0*r0+r1*r1+r2*r2+r3*r3+r4*r4+r5*r5+r6*r6+r7*r7;
            *(half8*)(Xs + ((size_t)(t16 * 4 + ks)) * 512 + L * 8) = h;
        }
        ssq += __shfl_xor(ssq, 16); ssq += __shfl_xor(ssq, 32);
        xr2 += __shfl_xor(xr2, 16); xr2 += __shfl_xor(xr2, 32);
        if (aq == 0) tsq[r] = (r < N_) ? ssq : inf_f();
        float m = xr2;
        m = fmaxf(m, __shfl_xor(m, 1)); m = fmaxf(m, __shfl_xor(m, 2));
        m = fmaxf(m, __shfl_xor(m, 4)); m = fmaxf(m, __shfl_xor(m, 8));
        if (L == 0) atomicMax(maxXr2, __float_as_uint(m));
    } else if (bx < XS_B + SAM_B) {
        int t16 = (bx - XS_B) * 4 + wv;
        int j = t16 * 16 + am;
        int n = j * SAMP_STRIDE + SAMP_OFF;       // < N_
        float ssq = 0.f;
        #pragma unroll
        for (int ks = 0; ks < 4; ++ks) {
            int c = ks * 32 + aq * 8;
            float4 a = *(const float4*)(X + (size_t)n * D_ + c);
            float4 b = *(const float4*)(X + (size_t)n * D_ + c + 4);
            half8 h;
            h[0]=(_Float16)a.x; h[1]=(_Float16)a.y; h[2]=(_Float16)a.z; h[3]=(_Float16)a.w;
            h[4]=(_Float16)b.x; h[5]=(_Float16)b.y; h[6]=(_Float16)b.z; h[7]=(_Float16)b.w;
            ssq += a.x*a.x + a.y*a.y + a.z*a.z + a.w*a.w
                 + b.x*b.x + b.y*b.y + b.z*b.z + b.w*b.w;
            *(half8*)(Xsam + ((size_t)(t16 * 4 + ks)) * 512 + L * 8) = h;
        }
        ssq += __shfl_xor(ssq, 16); ssq += __shfl_xor(ssq, 32);
        if (aq == 0) tsqS[j] = ssq;
    } else {
        int r = (bx - XS_B - SAM_B) * 4 + wv;     // < Q_
        float2 x = *(const float2*)(Qm + (size_t)r * D_ + 2 * L);
        __half h0 = __float2half(x.x), h1 = __float2half(x.y);
        size_t o = (size_t)r * D_ + 2 * L;
        Qh[o] = h0; Qh[o + 1] = h1;
        Qr[o]     = __float2half(x.x - __half2float(h0));
        Qr[o + 1] = __float2half(x.y - __half2float(h1));
        float s = x.x * x.x + x.y * x.y;
        s += __shfl_xor(s, 32); s += __shfl_xor(s, 16); s += __shfl_xor(s, 8);
        s += __shfl_xor(s, 4);  s += __shfl_xor(s, 2);  s += __shfl_xor(s, 1);
        if (L == 0) qsq[r] = s;
    }
}

// ---------------------------------------------------------- sample_T --------
__global__ __launch_bounds__(256, 2) void sample_T(
    const __half* __restrict__ Qh, const __half* __restrict__ Qr,
    const __half* __restrict__ Xsam, const float* __restrict__ tsqS,
    const float* __restrict__ qsq, const unsigned* __restrict__ maxXr2,
    float* __restrict__ Teff, float* __restrict__ rawT, float* __restrict__ EwA)
{
    __shared__ float sT[QTS][130];
    const int tid = threadIdx.x, L = tid & 63, wv = tid >> 6;
    const int qbase = blockIdx.x * QTS;
    const int nwv = wv * 64;
    const int am = L & 15, aq = L >> 4;

    half8 afh[4], afr[4];
    #pragma unroll
    for (int ks = 0; ks < 4; ++ks) {
        size_t o = (size_t)(qbase + am) * D_ + ks * 32 + aq * 8;
        afh[ks] = *(const half8*)(Qh + o);
        afr[ks] = *(const half8*)(Qr + o);
    }
    const half8* sp = (const half8*)Xsam;

    float t2a[4], t2b[4];
    #pragma unroll
    for (int rg = 0; rg < 4; ++rg) { t2a[rg] = inf_f(); t2b[rg] = inf_f(); }

    #pragma unroll 1
    for (int it = 0; it < SAMP_ITERS; ++it) {
        const int nbase = it * BN;
        const size_t segb = (size_t)((nbase + nwv) >> 4) * 4;
        floatx4 acc[4] = {};
        #pragma unroll
        for (int ks = 0; ks < 4; ++ks) {
            half8 bf[4];
            #pragma unroll
            for (int nt = 0; nt < 4; ++nt)
                bf[nt] = sp[(segb + nt * 4 + ks) * 64 + L];
            #pragma unroll
            for (int nt = 0; nt < 4; ++nt) {
                acc[nt] = __builtin_amdgcn_mfma_f32_16x16x32_f16(
                    afh[ks], bf[nt], acc[nt], 0, 0, 0);
                acc[nt] = __builtin_amdgcn_mfma_f32_16x16x32_f16(
                    afr[ks], bf[nt], acc[nt], 0, 0, 0);
            }
        }
        float ts[4];
        #pragma unroll
        for (int nt = 0; nt < 4; ++nt)
            ts[nt] = tsqS[nbase + nwv + nt * 16 + am];
        #pragma unroll
        for (int rg = 0; rg < 4; ++rg) {
            float m1 = t2a[rg], m2 = t2b[rg];
            #pragma unroll
            for (int nt = 0; nt < 4; ++nt) {
                float v = ts[nt] - 2.f * acc[nt][rg];
                if (v < m2) { if (v < m1) { m2 = m1; m1 = v; } else m2 = v; }
            }
            t2a[rg] = m1; t2b[rg] = m2;
        }
    }
    #pragma unroll
    for (int rg = 0; rg < 4; ++rg) {
        int q = aq * 4 + rg;
        sT[q][wv * 32 + am * 2 + 0] = t2a[rg];
        sT[q][wv * 32 + am * 2 + 1] = t2b[rg];
    }
    __syncthreads();

    #pragma unroll 1
    for (int j = 0; j < 4; ++j) {
        int q = wv * 4 + j;
        float a = sT[q][2 * L], b = sT[q][2 * L + 1];
        float g = 0.f;
        #pragma unroll 1
        for (int r = 0; r < 16; ++r) {
            float mn = fminf(a, b);
            mn = fminf(mn, __shfl_xor(mn, 32)); mn = fminf(mn, __shfl_xor(mn, 16));
            mn = fminf(mn, __shfl_xor(mn, 8));  mn = fminf(mn, __shfl_xor(mn, 4));
            mn = fminf(mn, __shfl_xor(mn, 2));  mn = fminf(mn, __shfl_xor(mn, 1));
            g = mn;
            ull ba = __ballot(a == g);
            if (ba) { if (L == __ffsll(ba) - 1) a = inf_f(); }
            else    { ull bb = __ballot(b == g); if (L == __ffsll(bb) - 1) b = inf_f(); }
        }
        if (L == 0) {
            int gq = qbase + q;
            float e = 2.f * sqrtf(qsq[gq]) * sqrtf(__uint_as_float(*maxXr2)) + 0.02f;
            rawT[gq] = g; EwA[gq] = e; Teff[gq] = g + e;
        }
    }
}

// ------------------------------------------------------------- main ---------
__global__ __launch_bounds__(256, 4) void knn_main(
    const __half* __restrict__ Qh, const __half* __restrict__ Qr,
    const __half* __restrict__ Xs, const float* __restrict__ tsq,
    const float* __restrict__ Teff, ull* __restrict__ candG,
    int* __restrict__ cntC, int* __restrict__ flagF)
{
    __shared__ ull candL[QT][CW];                 // 16 KB
    __shared__ int cntL[QT];

    const int tid = threadIdx.x, L = tid & 63, wv = tid >> 6;
    const int lb = blockIdx.x, ch = lb & 7;       // == XCD: one chunk per L2
    const int qbase = (lb >> 3) * QT, chBase = ch * CHUNK, nwv = wv * 64;
    const int am = L & 15, aq = L >> 4;

    if (tid < QT) cntL[tid] = 0;
    __syncthreads();                              // barrier #1

    float th[4];
    #pragma unroll
    for (int rg = 0; rg < 4; ++rg)
        th[rg] = Teff[qbase + aq * 4 + rg];
    float maxTh = fmaxf(fmaxf(th[0], th[1]), fmaxf(th[2], th[3]));
    const float negHalfMaxTh = -0.5f * maxTh - 1e-3f;   // strictly conservative

    half8 afh[4], afr[4];
    #pragma unroll
    for (int ks = 0; ks < 4; ++ks) {
        size_t o = (size_t)(qbase + am) * D_ + ks * 32 + aq * 8;
        afh[ks] = *(const half8*)(Qh + o);
        afr[ks] = *(const half8*)(Qr + o);
    }
    const half8* sp = (const half8*)Xs;

    half8 bc[4], bn[4];
    {
        size_t s0 = (size_t)((chBase + nwv) >> 4) * 4;
        #pragma unroll
        for (int nt = 0; nt < 4; ++nt)
            bc[nt] = sp[(s0 + nt * 4) * 64 + L];
    }

    #pragma unroll 1
    for (int it = 0; it < ITERS; ++it) {
        const int nbase = chBase + it * BN;
        const size_t sg  = (size_t)((nbase + nwv) >> 4) * 4;
        const size_t sgN = sg + 64;
        float ts[4];
        #pragma unroll
        for (int nt = 0; nt < 4; ++nt)
            ts[nt] = tsq[nbase + nwv + nt * 16 + am];

        floatx4 acc[4] = {};
        #pragma unroll
        for (int ks = 0; ks < 4; ++ks) {
            const bool hasNext = (ks < 3) || (it + 1 < ITERS);
            if (hasNext) {
                const size_t sb = (ks < 3) ? (sg + ks + 1) : sgN;
                #pragma unroll
                for (int nt = 0; nt < 4; ++nt)
                    bn[nt] = sp[(sb + nt * 4) * 64 + L];
            }
            #pragma unroll
            for (int nt = 0; nt < 4; ++nt) {
                acc[nt] = __builtin_amdgcn_mfma_f32_16x16x32_f16(
                    afh[ks], bc[nt], acc[nt], 0, 0, 0);
                acc[nt] = __builtin_amdgcn_mfma_f32_16x16x32_f16(
                    afr[ks], bc[nt], acc[nt], 0, 0, 0);
            }
            if (hasNext) {
                #pragma unroll
                for (int nt = 0; nt < 4; ++nt) bc[nt] = bn[nt];
            }
        }

        // cheap conservative detection on raw dot
        unsigned hit = 0;
        #pragma unroll
        for (int nt = 0; nt < 4; ++nt) {
            float mx = fmaxf(fmaxf(acc[nt][0], acc[nt][1]),
                             fmaxf(acc[nt][2], acc[nt][3]));
            float Gm = fmaf(0.5f, ts[nt], negHalfMaxTh);
            if (mx > Gm) hit |= 1u << nt;
        }
        if (__any(hit != 0)) {
            #pragma unroll
            for (int nt = 0; nt < 4; ++nt) {
                if (!__any(hit & (1u << nt))) continue;
                unsigned n = (unsigned)(nbase + nwv + nt * 16 + am);
                #pragma unroll
                for (int rg = 0; rg < 4; ++rg) {
                    float s = fmaf(-2.f, acc[nt][rg], ts[nt]);
                    if (s < th[rg]) {
                        int q = aq * 4 + rg;
                        int pos = atomicAdd(&cntL[q], 1);     // LDS atomic
                        if (pos < CW)
                            candL[q][pos] = pack_cand(s, n);
                        else
                            flagF[qbase + q] = 1;             // P ~ 1e-13
                    }
                }
            }
        }
    }

    __syncthreads();                              // barrier #2 (pre-dump)

    #pragma unroll 1
    for (int j = 0; j < 4; ++j) {
        int q = wv * 4 + j;
        int gq = qbase + q;
        int c = cntL[q];
        int cc = c < CW ? c : CW;
        ull* dst = candG + ((size_t)gq * NCH + ch) * CW;
        #pragma unroll
        for (int off = 0; off < CW; off += 64)
            if (off + L < cc) dst[off + L] = candL[q][off + L];
        if (L == 0) cntC[gq * NCH + ch] = cc;
    }
}

// ---------------------------------------- finalize (+ cheap fallback) -------
__global__ void finalize(const ull* __restrict__ candG, const int* __restrict__ cntC,
                         const int* __restrict__ flagF, const float* __restrict__ Qm,
                         const float* __restrict__ X, const float* __restrict__ tsq,
                         const float* __restrict__ rawT, const float* __restrict__ EwA,
                         const float* __restrict__ Ytr, float* __restrict__ out)
{
    __shared__ ull fb[4][256];                    // fallback collect buffers
    int L = threadIdx.x & 63;
    int wv = threadIdx.x >> 6;
    int q = blockIdx.x * 4 + wv;                  // one wave per query
    bool bad = (flagF[q] != 0);
    float result = 0.f;

    if (!bad) {
        int cg = (L < NCH) ? cntC[q * NCH + L] : 0;
        int ctot = cg;
        ctot += __shfl_xor(ctot, 32); ctot += __shfl_xor(ctot, 16);
        ctot += __shfl_xor(ctot, 8);  ctot += __shfl_xor(ctot, 4);
        ctot += __shfl_xor(ctot, 2);  ctot += __shfl_xor(ctot, 1);
        if (ctot < K_) bad = true;
        else {
            // merge chunk lists (each up to CW, in 64-blocks) -> top-64 approx
            ull s = DEADC;
            #pragma unroll 1
            for (int g = 0; g < NCH; ++g) {
                int c_g = __shfl(cg, g);
                const ull* cb = candG + ((size_t)q * NCH + g) * CW;
                #pragma unroll 1
                for (int off = 0; off < c_g; off += 64) {
                    ull v = (off + L < c_g) ? cb[off + L] : DEADC;
                    v = bitonic64(v, L);
                    ull w = __shfl(v, 63 - L);
                    s = bimerge64(u64min(s, w), L);
                }
            }
            int cr = ctot < 64 ? ctot : 64;
            unsigned n = (unsigned)(s & 0xffffffffu);
            ull pe = DEADC;
            if (L < cr) {
                const float4* xp = (const float4*)(X + (size_t)n * D_);
                const float4* qp = (const float4*)(Qm + (size_t)q * D_);
                float d = 0.f;
                #pragma unroll 8
                for (int i = 0; i < 32; ++i) {
                    float4 xv = xp[i], qv = qp[i];
                    d += qv.x * xv.x + qv.y * xv.y + qv.z * xv.z + qv.w * xv.w;
                }
                pe = pack_cand(tsq[n] - 2.f * d, n);
            }
            ull pe2 = bitonic64(pe, L);
            float exact31 = unpack_score(__shfl(pe2, K_ - 1));
            bool ok = exact31 < rawT[q];
            if (ctot > 64) {
                float A63 = unpack_score(__shfl(s, 63));
                ok = ok && (A63 - EwA[q] > exact31);
            }
            if (!ok) bad = true;
            else {
                float ys = 0.f;
                if (L < K_) ys = Ytr[(unsigned)(pe2 & 0xffffffffu)];
                ys += __shfl_xor(ys, 32); ys += __shfl_xor(ys, 16);
                ys += __shfl_xor(ys, 8);  ys += __shfl_xor(ys, 4);
                ys += __shfl_xor(ys, 2);  ys += __shfl_xor(ys, 1);
                result = ys * (1.f / K_);
            }
        }
    }

    if (bad) {   // exact fallback: thresholded single-pass collect + bisection
        const float4* qp = (const float4*)(Qm + (size_t)q * D_);
        float T = rawT[q] + EwA[q];
        float lo = 0.f, hi = 0.f;
        bool haveLo = false, haveHi = false;
        int cnt = 0;
        #pragma unroll 1
        for (int att = 0; att < 40; ++att) {
            cnt = 0;
            #pragma unroll 1
            for (int j = 0; j < NPAD / 64; ++j) {
                int n = j * 64 + L;
                float s = inf_f();
                if (n < N_) {
                    const float4* xp = (const float4*)(X + (size_t)n * D_);
                    float d = 0.f;
                    #pragma unroll 4
                    for (int i = 0; i < 32; ++i) {
                        float4 xv = xp[i], qv = qp[i];
                        d += qv.x * xv.x + qv.y * xv.y + qv.z * xv.z + qv.w * xv.w;
                    }
                    s = tsq[n] - 2.f * d;
                }
                bool want = s < T;
                ull m = __ballot(want);
                if (m) {
                    int pos = cnt + (int)__popcll(m & ((1ull << L) - 1ull));
                    if (want && pos < 256) fb[wv][pos] = pack_cand(s, (unsigned)n);
                    cnt += (int)__popcll(m);
                }
            }
            if (cnt >= K_ && cnt <= 256) break;
            if (cnt < K_) { lo = T; haveLo = true;
                T = haveHi ? 0.5f * (T + hi) : T + exp2f((float)att) * 0.5f; }
            else { hi = T; haveHi = true;
                T = haveLo ? 0.5f * (lo + T) : T - exp2f((float)att) * 0.5f; }
        }
        if (cnt >= K_ && cnt <= 256) {
            ull s64 = DEADC;
            #pragma unroll 1
            for (int off = 0; off < 256; off += 64) {
                if (off >= cnt) break;
                ull v = (off + L < cnt) ? fb[wv][off + L] : DEADC;
                v = bitonic64(v, L);
                ull w = __shfl(v, 63 - L);
                s64 = bimerge64(u64min(s64, w), L);
            }
            float ys = (L < K_) ? Ytr[(unsigned)(s64 & 0xffffffffu)] : 0.f;
            ys += __shfl_xor(ys, 32); ys += __shfl_xor(ys, 16);
            ys += __shfl_xor(ys, 8);  ys += __shfl_xor(ys, 4);
            ys += __shfl_xor(ys, 2);  ys += __shfl_xor(ys, 1);
            result = ys * (1.f / K_);
        } else {   // last resort: 32-round exact tournament (never expected)
            ull last = 0;
            float ysum = 0.f;
            for (int r = 0; r < K_; ++r) {
                ull best = DEADC;
                for (int j = 0; j < NPAD / 64; ++j) {
                    int n = j * 64 + L;
                    if (n < N_) {
                        const float4* xp = (const float4*)(X + (size_t)n * D_);
                        float d = 0.f;
                        #pragma unroll 4
                        for (int i = 0; i < 32; ++i) {
                            float4 xv = xp[i], qv = qp[i];
                            d += qv.x * xv.x + qv.y * xv.y + qv.z * xv.z + qv.w * xv.w;
                        }
                        ull k = pack_cand(tsq[n] - 2.f * d, n);
                        if (k > last && k < best) best = k;
                    }
                }
                best = u64min(best, __shfl_xor(best, 32));
                best = u64min(best, __shfl_xor(best, 16));
                best = u64min(best, __shfl_xor(best, 8));
                best = u64min(best, __shfl_xor(best, 4));
                best = u64min(best, __shfl_xor(best, 2));
                best = u64min(best, __shfl_xor(best, 1));
                if (L == 0) ysum += Ytr[(unsigned)(best & 0xffffffffu)];
                last = best;
            }
            result = ysum * (1.f / K_);
        }
    }
    if (L == 0) out[q] = result;
}

// ------------------------------------------------------------- launch -------
extern "C" void kernel_launch(void* const* d_in, const int* in_sizes, int n_in,
                              void* d_out, int out_size, void* d_ws, size_t ws_size,
                              hipStream_t stream)
{
    const float* Qm  = (const float*)d_in[0];   // [4096,128]
    const float* X   = (const float*)d_in[1];   // [100000,128]
    const float* Ytr = (const float*)d_in[2];   // [100000]
    float* out = (float*)d_out;                 // [4096]

    char* w = (char*)d_ws;
    auto alloc = [&](size_t bytes) {
        char* p = w; w += (bytes + 255) & ~(size_t)255; return p;
    };
    __half* Xs   = (__half*)  alloc((size_t)NPAD * D_ * 2);     // 25.7 MB
    __half* Qh   = (__half*)  alloc((size_t)Q_ * D_ * 2);       // 1 MB
    __half* Qr   = (__half*)  alloc((size_t)Q_ * D_ * 2);       // 1 MB
    float*  ts   = (float*)   alloc((size_t)NPAD * 4);          // 0.4 MB
    __half* Xsm  = (__half*)  alloc((size_t)SAMP_M * D_ * 2);   // 2 MB
    float*  tsS  = (float*)   alloc((size_t)SAMP_M * 4);        // 32 KB
    ull*    cd   = (ull*)     alloc((size_t)Q_ * NCH * CW * 8); // 33.6 MB
    int*    cnC  = (int*)     alloc((size_t)Q_ * NCH * 4);      // 128 KB
    int*    flg  = (int*)     alloc((size_t)Q_ * 4);            // 16 KB
    unsigned* mxr= (unsigned*)alloc(256);
    float*  Tef  = (float*)   alloc((size_t)Q_ * 4);
    float*  rwT  = (float*)   alloc((size_t)Q_ * 4);
    float*  Ew   = (float*)   alloc((size_t)Q_ * 4);
    float*  qs   = (float*)   alloc((size_t)Q_ * 4);            // total ~64 MB

    hipMemsetAsync(flg, 0, (size_t)Q_ * 4 + 256, stream);       // flg + mxr

    prep_all<<<XS_B + SAM_B + PQ_B, 256, 0, stream>>>(
        X, Qm, Xs, ts, mxr, Xsm, tsS, Qh, Qr, qs);
    sample_T<<<Q_ / QTS, 256, 0, stream>>>(Qh, Qr, Xsm, tsS, qs, mxr, Tef, rwT, Ew);
    knn_main<<<(Q_ / QT) * NCH, 256, 0, stream>>>(Qh, Qr, Xs, ts, Tef, cd, cnC, flg);
    finalize<<<Q_ / 4, 256, 0, stream>>>(cd, cnC, flg, Qm, X, ts, rwT, Ew, Ytr, out);
}

// Round 10
// 479.017 us; speedup vs baseline: 320.5091x; 1.1151x over previous
//
#include <hip/hip_runtime.h>
#include <hip/hip_fp16.h>
#include <cstdint>
#include <cstddef>

// KNN regressor v10 — v9 + pointer-increment addressing, branchless prefetch,
// pipelined sample_T, no memset node.
//   score[n] = tsq[n] - 2*dot(q, x_n)
// approx dot via fp16 split (qh+qr)·xh; |approx-exact| <= E_q = 2|q|·maxXr+0.02.
// Pipeline: prep_all -> sample_T -> knn_main -> finalize(+fallback).
// Selection skeleton identical to v9 (CW=128 overflow-proof, fixed thresholds,
// exact rescore + verify + cheap thresholded fallback).
//
// MFMA 16x16x32 f16 layouts (HW-verified, learn_hip m89/m91/m120):
//   A[m][k]: m=lane&15, k=(lane>>4)*8+j ; B[k][n]: n=lane&15, k=(lane>>4)*8+j
//   C[m][n]: n=lane&15, m=(lane>>4)*4+reg
// Xs swizzle: half-index (n_base)*128 + (nt*4+ks)*512 + L*8 holds the 8 halves
//   of row (n_base + nt*16 + (L&15)), k = ks*32+(L>>4)*8..+8.

constexpr int Q_  = 4096;
constexpr int N_  = 100000;
constexpr int D_  = 128;
constexpr int K_  = 32;

constexpr int QT    = 16;             // queries per block (one 16-row A tile)
constexpr int BN    = 256;            // n per iteration
constexpr int NCH   = 8;              // chunks == XCDs (ch = lb & 7)
constexpr int CHUNK = 12544;          // 49*256
constexpr int ITERS = CHUNK / BN;     // 49
constexpr int NPAD  = NCH * CHUNK;    // 100352
constexpr int CW    = 128;            // per-(query,chunk) capacity (P_ovf~1e-13)
constexpr int QTS   = 16;             // sample_T queries per block
constexpr int SAMP_M      = 8192;
constexpr int SAMP_STRIDE = 12;
constexpr int SAMP_OFF    = 5;        // max n = 8191*12+5 = 98297 < N_
constexpr int SAMP_ITERS  = SAMP_M / BN;   // 32

constexpr int XS_B  = NPAD / 64;      // 1568 blocks: Xs + tsq + mxArr
constexpr int SAM_B = SAMP_M / 64;    // 128 blocks: Xsam + tsqS
constexpr int PQ_B  = Q_ / 4;         // 1024 blocks: Qh/Qr/qsq + flagF zero
constexpr int MXN   = XS_B * 4;       // 6272 per-wave ||xr||^2 maxima

typedef __attribute__((ext_vector_type(8))) _Float16 half8;
typedef __attribute__((ext_vector_type(4))) float    floatx4;
typedef unsigned long long ull;

#define DEV __device__ __forceinline__
constexpr ull DEADC = ~0ull;

DEV ull pack_cand(float score, unsigned int n) {
    unsigned int s = __float_as_uint(score);
    s = (s & 0x80000000u) ? ~s : (s | 0x80000000u);   // monotone u32 key
    return ((ull)s << 32) | (ull)n;
}
DEV float unpack_score(ull k) {
    unsigned int s = (unsigned int)(k >> 32);
    s = (s & 0x80000000u) ? (s ^ 0x80000000u) : ~s;
    return __uint_as_float(s);
}
DEV ull u64min(ull a, ull b) { return a < b ? a : b; }
DEV float inf_f() { return __int_as_float(0x7f800000); }

DEV ull bitonic64(ull v, int L) {            // full sort, ascending
    #pragma unroll
    for (int k2 = 2; k2 <= 64; k2 <<= 1)
        #pragma unroll
        for (int j2 = k2 >> 1; j2 >= 1; j2 >>= 1) {
            ull o = __shfl_xor(v, j2);
            bool up = ((L & k2) == 0);
            bool lo = ((L & j2) == 0);
            ull mn = u64min(v, o), mx = v ^ o ^ mn;
            v = (lo == up) ? mn : mx;
        }
    return v;
}
DEV ull bimerge64(ull v, int L) {            // sort a bitonic seq, ascending
    #pragma unroll
    for (int j2 = 32; j2 >= 1; j2 >>= 1) {
        ull o = __shfl_xor(v, j2);
        ull mn = u64min(v, o), mx = v ^ o ^ mn;
        v = ((L & j2) == 0) ? mn : mx;
    }
    return v;
}

// ------------------------------------------------------------- prep_all -----
__global__ void prep_all(const float* __restrict__ X, const float* __restrict__ Qm,
                         __half* __restrict__ Xs, float* __restrict__ tsq,
                         float* __restrict__ mxArr,
                         __half* __restrict__ Xsam, float* __restrict__ tsqS,
                         __half* __restrict__ Qh, __half* __restrict__ Qr,
                         float* __restrict__ qsq, int* __restrict__ flagF)
{
    const int tid = threadIdx.x, L = tid & 63, wv = tid >> 6;
    const int bx = blockIdx.x;
    const int am = L & 15, aq = L >> 4;

    if (bx < XS_B) {
        int t16 = bx * 4 + wv;
        int r = t16 * 16 + am;
        float ssq = 0.f, xr2 = 0.f;
        #pragma unroll
        for (int ks = 0; ks < 4; ++ks) {
            int c = ks * 32 + aq * 8;
            float v0=0,v1=0,v2=0,v3=0,v4=0,v5=0,v6=0,v7=0;
            if (r < N_) {
                float4 a = *(const float4*)(X + (size_t)r * D_ + c);
                float4 b = *(const float4*)(X + (size_t)r * D_ + c + 4);
                v0=a.x; v1=a.y; v2=a.z; v3=a.w; v4=b.x; v5=b.y; v6=b.z; v7=b.w;
            }
            half8 h;
            h[0]=(_Float16)v0; h[1]=(_Float16)v1; h[2]=(_Float16)v2; h[3]=(_Float16)v3;
            h[4]=(_Float16)v4; h[5]=(_Float16)v5; h[6]=(_Float16)v6; h[7]=(_Float16)v7;
            float r0=v0-(float)h[0], r1=v1-(float)h[1], r2=v2-(float)h[2], r3=v3-(float)h[3];
            float r4=v4-(float)h[4], r5=v5-(float)h[5], r6=v6-(float)h[6], r7=v7-(float)h[7];
            ssq += v0*v0+v1*v1+v2*v2+v3*v3+v4*v4+v5*v5+v6*v6+v7*v7;
            xr2 += r0*r0+r1*r1+r2*r2+r3*r3+r4*r4+r5*r5+r6*r6+r7*r7;
            *(half8*)(Xs + ((size_t)(t16 * 4 + ks)) * 512 + L * 8) = h;
        }
        ssq += __shfl_xor(ssq, 16); ssq += __shfl_xor(ssq, 32);   // rowwise
        xr2 += __shfl_xor(xr2, 16); xr2 += __shfl_xor(xr2, 32);
        if (aq == 0) tsq[r] = (r < N_) ? ssq : inf_f();
        float m = xr2;                                            // max of 16 rows
        m = fmaxf(m, __shfl_xor(m, 1)); m = fmaxf(m, __shfl_xor(m, 2));
        m = fmaxf(m, __shfl_xor(m, 4)); m = fmaxf(m, __shfl_xor(m, 8));
        if (L == 0) mxArr[t16] = m;          // race-free per-wave slot
    } else if (bx < XS_B + SAM_B) {
        int t16 = (bx - XS_B) * 4 + wv;
        int j = t16 * 16 + am;
        int n = j * SAMP_STRIDE + SAMP_OFF;       // < N_
        float ssq = 0.f;
        #pragma unroll
        for (int ks = 0; ks < 4; ++ks) {
            int c = ks * 32 + aq * 8;
            float4 a = *(const float4*)(X + (size_t)n * D_ + c);
            float4 b = *(const float4*)(X + (size_t)n * D_ + c + 4);
            half8 h;
            h[0]=(_Float16)a.x; h[1]=(_Float16)a.y; h[2]=(_Float16)a.z; h[3]=(_Float16)a.w;
            h[4]=(_Float16)b.x; h[5]=(_Float16)b.y; h[6]=(_Float16)b.z; h[7]=(_Float16)b.w;
            ssq += a.x*a.x + a.y*a.y + a.z*a.z + a.w*a.w
                 + b.x*b.x + b.y*b.y + b.z*b.z + b.w*b.w;
            *(half8*)(Xsam + ((size_t)(t16 * 4 + ks)) * 512 + L * 8) = h;
        }
        ssq += __shfl_xor(ssq, 16); ssq += __shfl_xor(ssq, 32);
        if (aq == 0) tsqS[j] = ssq;
    } else {
        int r = (bx - XS_B - SAM_B) * 4 + wv;     // < Q_
        float2 x = *(const float2*)(Qm + (size_t)r * D_ + 2 * L);
        __half h0 = __float2half(x.x), h1 = __float2half(x.y);
        size_t o = (size_t)r * D_ + 2 * L;
        Qh[o] = h0; Qh[o + 1] = h1;
        Qr[o]     = __float2half(x.x - __half2float(h0));
        Qr[o + 1] = __float2half(x.y - __half2float(h1));
        float s = x.x * x.x + x.y * x.y;
        s += __shfl_xor(s, 32); s += __shfl_xor(s, 16); s += __shfl_xor(s, 8);
        s += __shfl_xor(s, 4);  s += __shfl_xor(s, 2);  s += __shfl_xor(s, 1);
        if (L == 0) { qsq[r] = s; flagF[r] = 0; }
    }
}

// ---------------------------------------------------------- sample_T --------
// T_q = 16th smallest of per-lane-top2 approx scores over the 8192 sample.
__global__ __launch_bounds__(256, 2) void sample_T(
    const __half* __restrict__ Qh, const __half* __restrict__ Qr,
    const __half* __restrict__ Xsam, const float* __restrict__ tsqS,
    const float* __restrict__ qsq, const float* __restrict__ mxArr,
    float* __restrict__ Teff, float* __restrict__ rawT, float* __restrict__ EwA)
{
    __shared__ float sT[QTS][130];
    const int tid = threadIdx.x, L = tid & 63, wv = tid >> 6;
    const int qbase = blockIdx.x * QTS;
    const int nwv = wv * 64;
    const int am = L & 15, aq = L >> 4;

    half8 afh[4], afr[4];
    #pragma unroll
    for (int ks = 0; ks < 4; ++ks) {
        size_t o = (size_t)(qbase + am) * D_ + ks * 32 + aq * 8;
        afh[ks] = *(const half8*)(Qh + o);
        afr[ks] = *(const half8*)(Qr + o);
    }

    float t2a[4], t2b[4];
    #pragma unroll
    for (int rg = 0; rg < 4; ++rg) { t2a[rg] = inf_f(); t2b[rg] = inf_f(); }

    const __half* bp = Xsam + (size_t)nwv * 128 + (size_t)L * 8;
    const float*  tp = tsqS + nwv + am;

    half8 bc[4], bn[4];
    #pragma unroll
    for (int nt = 0; nt < 4; ++nt)
        bc[nt] = *(const half8*)(bp + nt * 2048);

    #pragma unroll 1
    for (int it = 0; it < SAMP_ITERS; ++it) {
        float ts[4];
        #pragma unroll
        for (int nt = 0; nt < 4; ++nt) ts[nt] = tp[nt * 16];

        floatx4 acc[4] = {};
        #pragma unroll
        for (int ks = 0; ks < 4; ++ks) {
            const __half* pp = (ks < 3) ? (bp + (ks + 1) * 512) : (bp + 32768);
            #pragma unroll
            for (int nt = 0; nt < 4; ++nt)
                bn[nt] = *(const half8*)(pp + nt * 2048);
            #pragma unroll
            for (int nt = 0; nt < 4; ++nt) {
                acc[nt] = __builtin_amdgcn_mfma_f32_16x16x32_f16(
                    afh[ks], bc[nt], acc[nt], 0, 0, 0);
                acc[nt] = __builtin_amdgcn_mfma_f32_16x16x32_f16(
                    afr[ks], bc[nt], acc[nt], 0, 0, 0);
            }
            #pragma unroll
            for (int nt = 0; nt < 4; ++nt) bc[nt] = bn[nt];
        }
        #pragma unroll
        for (int rg = 0; rg < 4; ++rg) {
            float m1 = t2a[rg], m2 = t2b[rg];
            #pragma unroll
            for (int nt = 0; nt < 4; ++nt) {
                float v = ts[nt] - 2.f * acc[nt][rg];
                if (v < m2) { if (v < m1) { m2 = m1; m1 = v; } else m2 = v; }
            }
            t2a[rg] = m1; t2b[rg] = m2;
        }
        bp += 32768; tp += BN;
    }
    #pragma unroll
    for (int rg = 0; rg < 4; ++rg) {
        int q = aq * 4 + rg;
        sT[q][wv * 32 + am * 2 + 0] = t2a[rg];
        sT[q][wv * 32 + am * 2 + 1] = t2b[rg];
    }
    __syncthreads();

    // global max ||xr||^2 (each wave reduces the array independently)
    float mxr = 0.f;
    #pragma unroll 1
    for (int i = L; i < MXN; i += 64) mxr = fmaxf(mxr, mxArr[i]);
    mxr = fmaxf(mxr, __shfl_xor(mxr, 32)); mxr = fmaxf(mxr, __shfl_xor(mxr, 16));
    mxr = fmaxf(mxr, __shfl_xor(mxr, 8));  mxr = fmaxf(mxr, __shfl_xor(mxr, 4));
    mxr = fmaxf(mxr, __shfl_xor(mxr, 2));  mxr = fmaxf(mxr, __shfl_xor(mxr, 1));

    #pragma unroll 1
    for (int j = 0; j < 4; ++j) {
        int q = wv * 4 + j;
        float a = sT[q][2 * L], b = sT[q][2 * L + 1];
        float g = 0.f;
        #pragma unroll 1
        for (int r = 0; r < 16; ++r) {
            float mn = fminf(a, b);
            mn = fminf(mn, __shfl_xor(mn, 32)); mn = fminf(mn, __shfl_xor(mn, 16));
            mn = fminf(mn, __shfl_xor(mn, 8));  mn = fminf(mn, __shfl_xor(mn, 4));
            mn = fminf(mn, __shfl_xor(mn, 2));  mn = fminf(mn, __shfl_xor(mn, 1));
            g = mn;
            ull ba = __ballot(a == g);
            if (ba) { if (L == __ffsll(ba) - 1) a = inf_f(); }
            else    { ull bb = __ballot(b == g); if (L == __ffsll(bb) - 1) b = inf_f(); }
        }
        if (L == 0) {
            int gq = qbase + q;
            float e = 2.f * sqrtf(qsq[gq]) * sqrtf(mxr) + 0.02f;
            rawT[gq] = g; EwA[gq] = e; Teff[gq] = g + e;
        }
    }
}

// ------------------------------------------------------------- main ---------
__global__ __launch_bounds__(256, 4) void knn_main(
    const __half* __restrict__ Qh, const __half* __restrict__ Qr,
    const __half* __restrict__ Xs, const float* __restrict__ tsq,
    const float* __restrict__ Teff, ull* __restrict__ candG,
    int* __restrict__ cntC, int* __restrict__ flagF)
{
    __shared__ ull candL[QT][CW];                 // 16 KB
    __shared__ int cntL[QT];

    const int tid = threadIdx.x, L = tid & 63, wv = tid >> 6;
    const int lb = blockIdx.x, ch = lb & 7;       // == XCD: one chunk per L2
    const int qbase = (lb >> 3) * QT, chBase = ch * CHUNK, nwv = wv * 64;
    const int am = L & 15, aq = L >> 4;

    if (tid < QT) cntL[tid] = 0;
    __syncthreads();                              // barrier #1

    float th[4];
    #pragma unroll
    for (int rg = 0; rg < 4; ++rg)
        th[rg] = Teff[qbase + aq * 4 + rg];
    float maxTh = fmaxf(fmaxf(th[0], th[1]), fmaxf(th[2], th[3]));
    const float negHalfMaxTh = -0.5f * maxTh - 1e-3f;   // strictly conservative

    half8 afh[4], afr[4];
    #pragma unroll
    for (int ks = 0; ks < 4; ++ks) {
        size_t o = (size_t)(qbase + am) * D_ + ks * 32 + aq * 8;
        afh[ks] = *(const half8*)(Qh + o);
        afr[ks] = *(const half8*)(Qr + o);
    }

    // pointer-increment addressing (32-bit strides, no per-load 64-bit chains)
    const __half* bp = Xs + (size_t)(chBase + nwv) * 128 + (size_t)L * 8;
    const float*  tp = tsq + chBase + nwv + am;
    int n0 = chBase + nwv + am;

    half8 bc[4], bn[4];
    #pragma unroll
    for (int nt = 0; nt < 4; ++nt)
        bc[nt] = *(const half8*)(bp + nt * 2048);

    #pragma unroll 1
    for (int it = 0; it < ITERS; ++it) {
        float ts[4];
        #pragma unroll
        for (int nt = 0; nt < 4; ++nt) ts[nt] = tp[nt * 16];

        floatx4 acc[4] = {};
        #pragma unroll
        for (int ks = 0; ks < 4; ++ks) {
            // branchless prefetch: ks+1, or next iter's ks0 (Xs over-allocated)
            const __half* pp = (ks < 3) ? (bp + (ks + 1) * 512) : (bp + 32768);
            #pragma unroll
            for (int nt = 0; nt < 4; ++nt)
                bn[nt] = *(const half8*)(pp + nt * 2048);
            #pragma unroll
            for (int nt = 0; nt < 4; ++nt) {
                acc[nt] = __builtin_amdgcn_mfma_f32_16x16x32_f16(
                    afh[ks], bc[nt], acc[nt], 0, 0, 0);
                acc[nt] = __builtin_amdgcn_mfma_f32_16x16x32_f16(
                    afr[ks], bc[nt], acc[nt], 0, 0, 0);
            }
            #pragma unroll
            for (int nt = 0; nt < 4; ++nt) bc[nt] = bn[nt];
        }

        // cheap conservative detection on raw dot:
        //   score < th  <=>  dot > (ts - th)/2 ; group bound uses maxTh+slack
        unsigned hit = 0;
        #pragma unroll
        for (int nt = 0; nt < 4; ++nt) {
            float mx = fmaxf(fmaxf(acc[nt][0], acc[nt][1]),
                             fmaxf(acc[nt][2], acc[nt][3]));
            float Gm = fmaf(0.5f, ts[nt], negHalfMaxTh);
            if (mx > Gm) hit |= 1u << nt;
        }
        if (__any(hit != 0)) {
            #pragma unroll
            for (int nt = 0; nt < 4; ++nt) {
                if (!__any(hit & (1u << nt))) continue;
                unsigned n = (unsigned)(n0 + nt * 16);
                #pragma unroll
                for (int rg = 0; rg < 4; ++rg) {
                    float s = fmaf(-2.f, acc[nt][rg], ts[nt]);
                    if (s < th[rg]) {
                        int q = aq * 4 + rg;
                        int pos = atomicAdd(&cntL[q], 1);     // LDS atomic
                        if (pos < CW)
                            candL[q][pos] = pack_cand(s, n);
                        else
                            flagF[qbase + q] = 1;             // P ~ 1e-13
                    }
                }
            }
        }
        bp += 32768; tp += BN; n0 += BN;
    }

    __syncthreads();                              // barrier #2 (pre-dump)

    #pragma unroll 1
    for (int j = 0; j < 4; ++j) {
        int q = wv * 4 + j;
        int gq = qbase + q;
        int c = cntL[q];
        int cc = c < CW ? c : CW;
        ull* dst = candG + ((size_t)gq * NCH + ch) * CW;
        #pragma unroll
        for (int off = 0; off < CW; off += 64)
            if (off + L < cc) dst[off + L] = candL[q][off + L];
        if (L == 0) cntC[gq * NCH + ch] = cc;
    }
}

// ---------------------------------------- finalize (+ cheap fallback) -------
__global__ void finalize(const ull* __restrict__ candG, const int* __restrict__ cntC,
                         const int* __restrict__ flagF, const float* __restrict__ Qm,
                         const float* __restrict__ X, const float* __restrict__ tsq,
                         const float* __restrict__ rawT, const float* __restrict__ EwA,
                         const float* __restrict__ Ytr, float* __restrict__ out)
{
    __shared__ ull fb[4][256];                    // fallback collect buffers
    int L = threadIdx.x & 63;
    int wv = threadIdx.x >> 6;
    int q = blockIdx.x * 4 + wv;                  // one wave per query
    bool bad = (flagF[q] != 0);
    float result = 0.f;

    if (!bad) {
        int cg = (L < NCH) ? cntC[q * NCH + L] : 0;
        int ctot = cg;
        ctot += __shfl_xor(ctot, 32); ctot += __shfl_xor(ctot, 16);
        ctot += __shfl_xor(ctot, 8);  ctot += __shfl_xor(ctot, 4);
        ctot += __shfl_xor(ctot, 2);  ctot += __shfl_xor(ctot, 1);
        if (ctot < K_) bad = true;
        else {
            ull s = DEADC;
            #pragma unroll 1
            for (int g = 0; g < NCH; ++g) {
                int c_g = __shfl(cg, g);
                const ull* cb = candG + ((size_t)q * NCH + g) * CW;
                #pragma unroll 1
                for (int off = 0; off < c_g; off += 64) {
                    ull v = (off + L < c_g) ? cb[off + L] : DEADC;
                    v = bitonic64(v, L);
                    ull w = __shfl(v, 63 - L);
                    s = bimerge64(u64min(s, w), L);
                }
            }
            int cr = ctot < 64 ? ctot : 64;
            unsigned n = (unsigned)(s & 0xffffffffu);
            ull pe = DEADC;
            if (L < cr) {
                const float4* xp = (const float4*)(X + (size_t)n * D_);
                const float4* qp = (const float4*)(Qm + (size_t)q * D_);
                float d = 0.f;
                #pragma unroll 8
                for (int i = 0; i < 32; ++i) {
                    float4 xv = xp[i], qv = qp[i];
                    d += qv.x * xv.x + qv.y * xv.y + qv.z * xv.z + qv.w * xv.w;
                }
                pe = pack_cand(tsq[n] - 2.f * d, n);
            }
            ull pe2 = bitonic64(pe, L);
            float exact31 = unpack_score(__shfl(pe2, K_ - 1));
            bool ok = exact31 < rawT[q];
            if (ctot > 64) {
                float A63 = unpack_score(__shfl(s, 63));
                ok = ok && (A63 - EwA[q] > exact31);
            }
            if (!ok) bad = true;
            else {
                float ys = 0.f;
                if (L < K_) ys = Ytr[(unsigned)(pe2 & 0xffffffffu)];
                ys += __shfl_xor(ys, 32); ys += __shfl_xor(ys, 16);
                ys += __shfl_xor(ys, 8);  ys += __shfl_xor(ys, 4);
                ys += __shfl_xor(ys, 2);  ys += __shfl_xor(ys, 1);
                result = ys * (1.f / K_);
            }
        }
    }

    if (bad) {   // exact fallback: thresholded single-pass collect + bisection
        const float4* qp = (const float4*)(Qm + (size_t)q * D_);
        float T = rawT[q] + EwA[q];
        float lo = 0.f, hi = 0.f;
        bool haveLo = false, haveHi = false;
        int cnt = 0;
        #pragma unroll 1
        for (int att = 0; att < 40; ++att) {
            cnt = 0;
            #pragma unroll 1
            for (int j = 0; j < NPAD / 64; ++j) {
                int n = j * 64 + L;
                float s = inf_f();
                if (n < N_) {
                    const float4* xp = (const float4*)(X + (size_t)n * D_);
                    float d = 0.f;
                    #pragma unroll 4
                    for (int i = 0; i < 32; ++i) {
                        float4 xv = xp[i], qv = qp[i];
                        d += qv.x * xv.x + qv.y * xv.y + qv.z * xv.z + qv.w * xv.w;
                    }
                    s = tsq[n] - 2.f * d;
                }
                bool want = s < T;
                ull m = __ballot(want);
                if (m) {
                    int pos = cnt + (int)__popcll(m & ((1ull << L) - 1ull));
                    if (want && pos < 256) fb[wv][pos] = pack_cand(s, (unsigned)n);
                    cnt += (int)__popcll(m);
                }
            }
            if (cnt >= K_ && cnt <= 256) break;
            if (cnt < K_) { lo = T; haveLo = true;
                T = haveHi ? 0.5f * (T + hi) : T + exp2f((float)att) * 0.5f; }
            else { hi = T; haveHi = true;
                T = haveLo ? 0.5f * (lo + T) : T - exp2f((float)att) * 0.5f; }
        }
        if (cnt >= K_ && cnt <= 256) {
            ull s64 = DEADC;
            #pragma unroll 1
            for (int off = 0; off < 256; off += 64) {
                if (off >= cnt) break;
                ull v = (off + L < cnt) ? fb[wv][off + L] : DEADC;
                v = bitonic64(v, L);
                ull w = __shfl(v, 63 - L);
                s64 = bimerge64(u64min(s64, w), L);
            }
            float ys = (L < K_) ? Ytr[(unsigned)(s64 & 0xffffffffu)] : 0.f;
            ys += __shfl_xor(ys, 32); ys += __shfl_xor(ys, 16);
            ys += __shfl_xor(ys, 8);  ys += __shfl_xor(ys, 4);
            ys += __shfl_xor(ys, 2);  ys += __shfl_xor(ys, 1);
            result = ys * (1.f / K_);
        } else {   // last resort: 32-round exact tournament (never expected)
            ull last = 0;
            float ysum = 0.f;
            for (int r = 0; r < K_; ++r) {
                ull best = DEADC;
                for (int j = 0; j < NPAD / 64; ++j) {
                    int n = j * 64 + L;
                    if (n < N_) {
                        const float4* xp = (const float4*)(X + (size_t)n * D_);
                        float d = 0.f;
                        #pragma unroll 4
                        for (int i = 0; i < 32; ++i) {
                            float4 xv = xp[i], qv = qp[i];
                            d += qv.x * xv.x + qv.y * xv.y + qv.z * xv.z + qv.w * xv.w;
                        }
                        ull k = pack_cand(tsq[n] - 2.f * d, n);
                        if (k > last && k < best) best = k;
                    }
                }
                best = u64min(best, __shfl_xor(best, 32));
                best = u64min(best, __shfl_xor(best, 16));
                best = u64min(best, __shfl_xor(best, 8));
                best = u64min(best, __shfl_xor(best, 4));
                best = u64min(best, __shfl_xor(best, 2));
                best = u64min(best, __shfl_xor(best, 1));
                if (L == 0) ysum += Ytr[(unsigned)(best & 0xffffffffu)];
                last = best;
            }
            result = ysum * (1.f / K_);
        }
    }
    if (L == 0) out[q] = result;
}

// ------------------------------------------------------------- launch -------
extern "C" void kernel_launch(void* const* d_in, const int* in_sizes, int n_in,
                              void* d_out, int out_size, void* d_ws, size_t ws_size,
                              hipStream_t stream)
{
    const float* Qm  = (const float*)d_in[0];   // [4096,128]
    const float* X   = (const float*)d_in[1];   // [100000,128]
    const float* Ytr = (const float*)d_in[2];   // [100000]
    float* out = (float*)d_out;                 // [4096]

    char* w = (char*)d_ws;
    auto alloc = [&](size_t bytes) {
        char* p = w; w += (bytes + 255) & ~(size_t)255; return p;
    };
    __half* Xs   = (__half*)  alloc((size_t)(NPAD + BN) * D_ * 2);   // 25.8 MB (+prefetch pad)
    __half* Qh   = (__half*)  alloc((size_t)Q_ * D_ * 2);            // 1 MB
    __half* Qr   = (__half*)  alloc((size_t)Q_ * D_ * 2);            // 1 MB
    float*  ts   = (float*)   alloc((size_t)NPAD * 4);               // 0.4 MB
    __half* Xsm  = (__half*)  alloc((size_t)(SAMP_M + BN) * D_ * 2); // 2.1 MB (+pad)
    float*  tsS  = (float*)   alloc((size_t)SAMP_M * 4);             // 32 KB
    ull*    cd   = (ull*)     alloc((size_t)Q_ * NCH * CW * 8);      // 33.6 MB
    int*    cnC  = (int*)     alloc((size_t)Q_ * NCH * 4);           // 128 KB
    int*    flg  = (int*)     alloc((size_t)Q_ * 4);                 // 16 KB
    float*  mxA  = (float*)   alloc((size_t)MXN * 4);                // 25 KB
    float*  Tef  = (float*)   alloc((size_t)Q_ * 4);
    float*  rwT  = (float*)   alloc((size_t)Q_ * 4);
    float*  Ew   = (float*)   alloc((size_t)Q_ * 4);
    float*  qs   = (float*)   alloc((size_t)Q_ * 4);                 // total ~64 MB

    prep_all<<<XS_B + SAM_B + PQ_B, 256, 0, stream>>>(
        X, Qm, Xs, ts, mxA, Xsm, tsS, Qh, Qr, qs, flg);
    sample_T<<<Q_ / QTS, 256, 0, stream>>>(Qh, Qr, Xsm, tsS, qs, mxA, Tef, rwT, Ew);
    knn_main<<<(Q_ / QT) * NCH, 256, 0, stream>>>(Qh, Qr, Xs, ts, Tef, cd, cnC, flg);
    finalize<<<Q_ / 4, 256, 0, stream>>>(cd, cnC, flg, Qm, X, ts, rwT, Ew, Ytr, out);
}